// Round 1
// baseline (116.345 us; speedup 1.0000x reference)
//
#include <hip/hip_runtime.h>
#include <hip/hip_bf16.h>

#define NB 16      // batch
#define TT 1024    // Tq == Tk
#define NH 4       // heads
#define HD 6       // head dim
#define DM 24      // model dim

// ---------- helpers ----------

__device__ __forceinline__ float bf_as_f32(unsigned short u) {
  return __uint_as_float(((unsigned int)u) << 16);
}

// load element idx from tensor p, converting from bf16 if isb != 0
__device__ __forceinline__ float ldf(const void* p, int idx, int isb) {
  if (isb) return bf_as_f32(((const unsigned short*)p)[idx]);
  return ((const float*)p)[idx];
}

// ---------- kernel A: detect whether float tensors are bf16 or f32 ----------
// Reinterpret first 8192 elements of X as bf16. If underlying storage is f32,
// every even "bf16" is random mantissa bits -> random exponent -> max is
// astronomically large. If underlying is bf16, values are N(0,1)-ish (<~6).
__global__ void detect_dtype_kernel(const void* x, int* flag) {
  __shared__ float red[256];
  const unsigned short* xb = (const unsigned short*)x;
  float m = 0.f;
  for (int i = threadIdx.x; i < 8192; i += 256) {
    float v = bf_as_f32(xb[i]);
    float a = fabsf(v);
    if (!(a < 1e30f)) a = 1e30f;  // NaN/Inf -> huge
    m = fmaxf(m, a);
  }
  red[threadIdx.x] = m;
  __syncthreads();
  for (int s = 128; s > 0; s >>= 1) {
    if (threadIdx.x < s) red[threadIdx.x] = fmaxf(red[threadIdx.x], red[threadIdx.x + s]);
    __syncthreads();
  }
  if (threadIdx.x == 0) flag[0] = (red[0] > 1e6f) ? 0 : 1;  // 1 => bf16
}

// ---------- kernel B: fused Q/K/V projection ----------
// Q[b,h,t,d] = sum_c X[b,t,c] * Wq[h*6+d, c]   (torch Linear: x @ W.T)
// K,V likewise from X_en. Output layout: [B][H][T][HD] contiguous f32.
__global__ __launch_bounds__(256) void qkv_kernel(
    const void* __restrict__ X, const void* __restrict__ Xen,
    const void* __restrict__ Wq, const void* __restrict__ Wk,
    const void* __restrict__ Wv, const int* __restrict__ flag,
    float* __restrict__ Q, float* __restrict__ K, float* __restrict__ V) {
  __shared__ float wq[DM * DM], wk[DM * DM], wv[DM * DM];
  const int isb = flag[0];
  for (int i = threadIdx.x; i < DM * DM; i += 256) {
    wq[i] = ldf(Wq, i, isb);
    wk[i] = ldf(Wk, i, isb);
    wv[i] = ldf(Wv, i, isb);
  }
  __syncthreads();
  const int r = blockIdx.x * 256 + threadIdx.x;  // row in [0, NB*TT)
  if (r >= NB * TT) return;
  float x[DM], xe[DM];
#pragma unroll
  for (int c = 0; c < DM; ++c) {
    x[c]  = ldf(X,   r * DM + c, isb);
    xe[c] = ldf(Xen, r * DM + c, isb);
  }
  const int b = r >> 10;       // TT = 1024
  const int t = r & (TT - 1);
#pragma unroll
  for (int j = 0; j < DM; ++j) {
    float aq = 0.f, ak = 0.f, av = 0.f;
#pragma unroll
    for (int c = 0; c < DM; ++c) {
      aq = fmaf(x[c],  wq[j * DM + c], aq);
      ak = fmaf(xe[c], wk[j * DM + c], ak);
      av = fmaf(xe[c], wv[j * DM + c], av);
    }
    const int h = j / HD, d = j - h * HD;
    const int off = ((b * NH + h) * TT + t) * HD + d;
    Q[off] = aq;
    K[off] = ak;
    V[off] = av;
  }
}

// ---------- kernel C: attention per (b, h, q-tile) ----------
// Two-pass softmax; K,V for the head staged in LDS (rows padded to 8 floats).
__device__ __forceinline__ float dot6(const float* __restrict__ q,
                                      const float* __restrict__ k) {
  float s = q[0] * k[0];
  s = fmaf(q[1], k[1], s);
  s = fmaf(q[2], k[2], s);
  s = fmaf(q[3], k[3], s);
  s = fmaf(q[4], k[4], s);
  s = fmaf(q[5], k[5], s);
  return s;
}

__global__ __launch_bounds__(256) void attn_kernel(
    const float* __restrict__ Q, const float* __restrict__ K,
    const float* __restrict__ V, float* __restrict__ O) {
  __shared__ float Ks[TT][8];
  __shared__ float Vs[TT][8];
  const int tile = blockIdx.x & 3;   // 4 q-tiles of 256 rows
  const int bh = blockIdx.x >> 2;    // b*NH + h
  const float* __restrict__ Kh = K + (size_t)bh * TT * HD;
  const float* __restrict__ Vh = V + (size_t)bh * TT * HD;
  for (int i = threadIdx.x; i < TT * HD; i += 256) {
    const int k = i / HD, d = i - k * HD;
    Ks[k][d] = Kh[i];
    Vs[k][d] = Vh[i];
  }
  __syncthreads();

  const int q = tile * 256 + threadIdx.x;
  const float scale = 0.40824829046386307f;  // 1/sqrt(6)
  float qv[HD];
  const float* __restrict__ Qr = Q + ((size_t)bh * TT + q) * HD;
#pragma unroll
  for (int d = 0; d < HD; ++d) qv[d] = Qr[d] * scale;

  // pass 1: row max (4 independent chains)
  float m0 = -1e30f, m1 = -1e30f, m2 = -1e30f, m3 = -1e30f;
  for (int k = 0; k < TT; k += 4) {
    m0 = fmaxf(m0, dot6(qv, Ks[k + 0]));
    m1 = fmaxf(m1, dot6(qv, Ks[k + 1]));
    m2 = fmaxf(m2, dot6(qv, Ks[k + 2]));
    m3 = fmaxf(m3, dot6(qv, Ks[k + 3]));
  }
  const float m = fmaxf(fmaxf(m0, m1), fmaxf(m2, m3));

  // pass 2: exp + accumulate (independent exps; 7 accumulation chains x2 unroll)
  float l0 = 0.f, l1 = 0.f;
  float acc[HD] = {0.f, 0.f, 0.f, 0.f, 0.f, 0.f};
  for (int k = 0; k < TT; k += 2) {
    const float p0 = __expf(dot6(qv, Ks[k + 0]) - m);
    const float p1 = __expf(dot6(qv, Ks[k + 1]) - m);
    l0 += p0;
    l1 += p1;
#pragma unroll
    for (int d = 0; d < HD; ++d) {
      acc[d] = fmaf(p0, Vs[k + 0][d], acc[d]);
      acc[d] = fmaf(p1, Vs[k + 1][d], acc[d]);
    }
  }
  const float inv = 1.f / (l0 + l1);
  const int b = bh >> 2, h = bh & (NH - 1);
  float* __restrict__ Or = O + ((size_t)(b * TT + q)) * DM + h * HD;
#pragma unroll
  for (int d = 0; d < HD; ++d) Or[d] = acc[d] * inv;
}

// ---------- kernel D: output projection ----------
__global__ __launch_bounds__(256) void outproj_kernel(
    const float* __restrict__ O, const void* __restrict__ Wo,
    const int* __restrict__ flag, void* __restrict__ out) {
  __shared__ float w[DM * DM];
  const int isb = flag[0];
  for (int i = threadIdx.x; i < DM * DM; i += 256) w[i] = ldf(Wo, i, isb);
  __syncthreads();
  const int r = blockIdx.x * 256 + threadIdx.x;
  if (r >= NB * TT) return;
  float x[DM];
#pragma unroll
  for (int c = 0; c < DM; ++c) x[c] = O[r * DM + c];
#pragma unroll
  for (int j = 0; j < DM; ++j) {
    float a = 0.f;
#pragma unroll
    for (int c = 0; c < DM; ++c) a = fmaf(x[c], w[j * DM + c], a);
    if (isb) {
      ((__hip_bfloat16*)out)[r * DM + j] = __float2bfloat16(a);
    } else {
      ((float*)out)[r * DM + j] = a;
    }
  }
}

// ---------- launch ----------
extern "C" void kernel_launch(void* const* d_in, const int* in_sizes, int n_in,
                              void* d_out, int out_size, void* d_ws, size_t ws_size,
                              hipStream_t stream) {
  const void* X   = d_in[0];
  const void* Xen = d_in[1];
  // d_in[2] = I_m : dead in the reference (masked_fill result discarded)
  const void* Wq = d_in[3];
  const void* Wk = d_in[4];
  const void* Wv = d_in[5];
  const void* Wo = d_in[6];

  char* ws = (char*)d_ws;
  int* flag = (int*)ws;
  float* Q = (float*)(ws + 256);
  float* K = Q + (size_t)NB * TT * DM;  // NB*NH*TT*HD == NB*TT*24
  float* V = K + (size_t)NB * TT * DM;
  float* O = V + (size_t)NB * TT * DM;

  detect_dtype_kernel<<<1, 256, 0, stream>>>(X, flag);
  qkv_kernel<<<(NB * TT) / 256, 256, 0, stream>>>(X, Xen, Wq, Wk, Wv, flag, Q, K, V);
  attn_kernel<<<NB * NH * 4, 256, 0, stream>>>(Q, K, V, O);
  outproj_kernel<<<(NB * TT) / 256, 256, 0, stream>>>(O, Wo, flag, d_out);
}

// Round 3
// 46.464 us; speedup vs baseline: 2.5040x; 2.5040x over previous
//
#include <hip/hip_runtime.h>
#include <hip/hip_bf16.h>

#define NB 16      // batch
#define TT 1024    // Tq == Tk
#define NH 4       // heads
#define HD 6       // head dim
#define DM 24      // model dim

// (1/sqrt(6)) * log2(e) -- folded into Wq so attention works in exp2 domain
#define QSC 0.5889785f
// conservative upper bound on any log2-domain score; softmax is invariant to it
#define MBIAS 32.0f

// NOTE: dtype = f32 confirmed at runtime (round 1 passed with f32 reads AND
// f32 writes validated by the harness). Detection kernel removed.

// ---------- kernel 1: fused Q/K/V projection ----------
// grid = (NB*TT/64) * 3 = 768 blocks, 256 threads.
// block handles 64 rows of ONE matrix (0=Q,1=K,2=V); thread = (row, head).
__global__ __launch_bounds__(256, 4) void qkv_kernel(
    const float* __restrict__ X, const float* __restrict__ Xen,
    const float* __restrict__ Wq, const float* __restrict__ Wk,
    const float* __restrict__ Wv,
    float* __restrict__ Q, float* __restrict__ K, float* __restrict__ V) {
  __shared__ float w[DM * DM];
  const int mat = blockIdx.x % 3;
  const int rb = (blockIdx.x / 3) * 64;
  const float* __restrict__ W = (mat == 0) ? Wq : (mat == 1 ? Wk : Wv);
  const float* __restrict__ Xs = (mat == 0) ? X : Xen;
  float* __restrict__ Out = (mat == 0) ? Q : (mat == 1 ? K : V);
  const float sc = (mat == 0) ? QSC : 1.0f;
  for (int i = threadIdx.x; i < DM * DM; i += 256) w[i] = W[i] * sc;
  __syncthreads();

  const int rl = threadIdx.x >> 2;  // 0..63
  const int h = threadIdx.x & 3;    // head
  const int r = rb + rl;            // global row in [0, NB*TT)
  float x[DM];
  const float4* __restrict__ xr = (const float4*)(Xs + (size_t)r * DM);
#pragma unroll
  for (int i = 0; i < 6; ++i) {
    float4 t = xr[i];
    x[4 * i] = t.x; x[4 * i + 1] = t.y; x[4 * i + 2] = t.z; x[4 * i + 3] = t.w;
  }
  const int b = r >> 10, t = r & (TT - 1);
  float o[HD];
#pragma unroll
  for (int d = 0; d < HD; ++d) {
    const int j = h * HD + d;
    float a = 0.f;
#pragma unroll
    for (int c = 0; c < DM; ++c) a = fmaf(x[c], w[j * DM + c], a);
    o[d] = a;
  }
  float* __restrict__ Or = Out + (((size_t)(b * NH + h) * TT) + t) * HD;
#pragma unroll
  for (int d = 0; d < HD; ++d) Or[d] = o[d];
}

// ---------- kernel 2: attention ----------
// One-pass softmax in exp2 domain with fixed bias MBIAS (no row-max pass:
// p_i = 2^(s_i - M); ratios are exact, M bounds scores so no overflow, and
// l >= 2^-55 so no underflow. Identical result up to fp rounding.)
// Block = 512 threads: 128 queries x 4 key-splits. Each lane s covers keys
// k = s*256 + i. KV packed per key as 12 floats -> 3x ds_read_b128,
// 4 distinct broadcast addresses/wave on disjoint banks.
#define QB 128
#define SPLIT 4
#define KPT (TT / SPLIT)  // 256

__global__ __launch_bounds__(512, 4) void attn_kernel(
    const float* __restrict__ Q, const float* __restrict__ K,
    const float* __restrict__ V, float* __restrict__ O) {
  __shared__ float KV[TT * 12];  // [key interleaved]: k0..k5, v0..v5
  const int tile = blockIdx.x & 7;
  const int bh = blockIdx.x >> 3;
  const float* __restrict__ Kh = K + (size_t)bh * TT * HD;
  const float* __restrict__ Vh = V + (size_t)bh * TT * HD;

  for (int r = threadIdx.x; r < TT; r += 512) {
    const int i = r & (KPT - 1), s = r >> 8;  // key r = s*KPT + i
    const float2* __restrict__ k2 = (const float2*)(Kh + (size_t)r * HD);
    const float2* __restrict__ v2 = (const float2*)(Vh + (size_t)r * HD);
    float2 a = k2[0], b = k2[1], c = k2[2];
    float2 d = v2[0], e = v2[1], f = v2[2];
    float4* __restrict__ dst = (float4*)&KV[(i * SPLIT + s) * 12];
    dst[0] = make_float4(a.x, a.y, b.x, b.y);
    dst[1] = make_float4(c.x, c.y, d.x, d.y);
    dst[2] = make_float4(e.x, e.y, f.x, f.y);
  }
  __syncthreads();

  const int s = threadIdx.x & 3;
  const int q = tile * QB + (threadIdx.x >> 2);
  const float* __restrict__ Qr = Q + ((size_t)bh * TT + q) * HD;
  const float q0 = Qr[0], q1 = Qr[1], q2 = Qr[2], q3 = Qr[3], q4 = Qr[4],
              q5 = Qr[5];

  float l = 0.f;
  float a0 = 0.f, a1 = 0.f, a2 = 0.f, a3 = 0.f, a4 = 0.f, a5 = 0.f;
  const float4* __restrict__ kv = (const float4*)&KV[s * 12];
#pragma unroll 4
  for (int i = 0; i < KPT; ++i) {
    const float4 A = kv[i * 12 + 0];
    const float4 B = kv[i * 12 + 1];
    const float4 C = kv[i * 12 + 2];
    float t = fmaf(q0, A.x, -MBIAS);
    t = fmaf(q1, A.y, t);
    t = fmaf(q2, A.z, t);
    t = fmaf(q3, A.w, t);
    t = fmaf(q4, B.x, t);
    t = fmaf(q5, B.y, t);
    const float p = __builtin_amdgcn_exp2f(t);
    l += p;
    a0 = fmaf(p, B.z, a0);
    a1 = fmaf(p, B.w, a1);
    a2 = fmaf(p, C.x, a2);
    a3 = fmaf(p, C.y, a3);
    a4 = fmaf(p, C.z, a4);
    a5 = fmaf(p, C.w, a5);
  }

  // combine the 4 key-splits (lanes differing in bits 0-1)
#define RED(v)                 \
  v += __shfl_xor(v, 1);       \
  v += __shfl_xor(v, 2);
  RED(l) RED(a0) RED(a1) RED(a2) RED(a3) RED(a4) RED(a5)
#undef RED

  if (s == 0) {
    const float inv = 1.f / l;
    const int b = bh >> 2, h = bh & (NH - 1);
    float* __restrict__ Or =
        O + ((size_t)(b * TT + q)) * DM + h * HD;
    Or[0] = a0 * inv;
    Or[1] = a1 * inv;
    Or[2] = a2 * inv;
    Or[3] = a3 * inv;
    Or[4] = a4 * inv;
    Or[5] = a5 * inv;
  }
}

// ---------- kernel 3: output projection ----------
// grid = NB*TT/32 = 512 blocks, 256 threads: 32 rows x 8 j-groups of 3.
__global__ __launch_bounds__(256, 4) void outproj_kernel(
    const float* __restrict__ O, const float* __restrict__ Wo,
    float* __restrict__ out) {
  __shared__ float w[DM * DM];
  for (int i = threadIdx.x; i < DM * DM; i += 256) w[i] = Wo[i];
  __syncthreads();
  const int rl = threadIdx.x >> 3, u = threadIdx.x & 7;
  const int r = blockIdx.x * 32 + rl;
  float x[DM];
  const float4* __restrict__ xr = (const float4*)(O + (size_t)r * DM);
#pragma unroll
  for (int i = 0; i < 6; ++i) {
    float4 t = xr[i];
    x[4 * i] = t.x; x[4 * i + 1] = t.y; x[4 * i + 2] = t.z; x[4 * i + 3] = t.w;
  }
#pragma unroll
  for (int jj = 0; jj < 3; ++jj) {
    const int j = u * 3 + jj;
    float a = 0.f;
#pragma unroll
    for (int c = 0; c < DM; ++c) a = fmaf(x[c], w[j * DM + c], a);
    out[(size_t)r * DM + j] = a;
  }
}

// ---------- launch ----------
extern "C" void kernel_launch(void* const* d_in, const int* in_sizes, int n_in,
                              void* d_out, int out_size, void* d_ws, size_t ws_size,
                              hipStream_t stream) {
  const float* X = (const float*)d_in[0];
  const float* Xen = (const float*)d_in[1];
  // d_in[2] = I_m : dead in the reference (masked_fill result discarded)
  const float* Wq = (const float*)d_in[3];
  const float* Wk = (const float*)d_in[4];
  const float* Wv = (const float*)d_in[5];
  const float* Wo = (const float*)d_in[6];

  float* Q = (float*)d_ws;
  float* K = Q + (size_t)NB * TT * DM;
  float* V = K + (size_t)NB * TT * DM;
  float* O = V + (size_t)NB * TT * DM;

  qkv_kernel<<<(NB * TT / 64) * 3, 256, 0, stream>>>(X, Xen, Wq, Wk, Wv, Q, K, V);
  attn_kernel<<<NB * NH * (TT / QB), 512, 0, stream>>>(Q, K, V, O);
  outproj_kernel<<<NB * TT / 32, 256, 0, stream>>>(O, Wo, (float*)d_out);
}

// Round 4
// 45.915 us; speedup vs baseline: 2.5339x; 1.0120x over previous
//
#include <hip/hip_runtime.h>
#include <hip/hip_bf16.h>

#define NB 16      // batch
#define TT 1024    // Tq == Tk
#define NH 4       // heads
#define HD 6       // head dim
#define DM 24      // model dim

// (1/sqrt(6)) * log2(e) -- folded into Wq so attention works in exp2 domain
#define QSC 0.5889785f
// conservative upper bound on any log2-domain score; softmax invariant to it
#define MBIAS 32.0f

typedef float v2f __attribute__((ext_vector_type(2)));

// ---------- kernel 1: fused Q/K/V projection (unchanged from round 3) ----------
__global__ __launch_bounds__(256, 4) void qkv_kernel(
    const float* __restrict__ X, const float* __restrict__ Xen,
    const float* __restrict__ Wq, const float* __restrict__ Wk,
    const float* __restrict__ Wv,
    float* __restrict__ Q, float* __restrict__ K, float* __restrict__ V) {
  __shared__ float w[DM * DM];
  const int mat = blockIdx.x % 3;
  const int rb = (blockIdx.x / 3) * 64;
  const float* __restrict__ W = (mat == 0) ? Wq : (mat == 1 ? Wk : Wv);
  const float* __restrict__ Xs = (mat == 0) ? X : Xen;
  float* __restrict__ Out = (mat == 0) ? Q : (mat == 1 ? K : V);
  const float sc = (mat == 0) ? QSC : 1.0f;
  for (int i = threadIdx.x; i < DM * DM; i += 256) w[i] = W[i] * sc;
  __syncthreads();

  const int rl = threadIdx.x >> 2;
  const int h = threadIdx.x & 3;
  const int r = rb + rl;
  float x[DM];
  const float4* __restrict__ xr = (const float4*)(Xs + (size_t)r * DM);
#pragma unroll
  for (int i = 0; i < 6; ++i) {
    float4 t = xr[i];
    x[4 * i] = t.x; x[4 * i + 1] = t.y; x[4 * i + 2] = t.z; x[4 * i + 3] = t.w;
  }
  const int b = r >> 10, t = r & (TT - 1);
  float o[HD];
#pragma unroll
  for (int d = 0; d < HD; ++d) {
    const int j = h * HD + d;
    float a = 0.f;
#pragma unroll
    for (int c = 0; c < DM; ++c) a = fmaf(x[c], w[j * DM + c], a);
    o[d] = a;
  }
  float* __restrict__ Or = Out + (((size_t)(b * NH + h) * TT) + t) * HD;
#pragma unroll
  for (int d = 0; d < HD; ++d) Or[d] = o[d];
}

// ---------- kernel 2: attention, packed 2-keys-per-iteration ----------
// Block = 512 thr: 128 queries x 4 key-splits; split s covers keys
// [s*256, s*256+256) as 128 key-PAIRS. LDS slot per pair (stride 28 floats =
// 112 B, 16B-aligned): K dims interleaved (kA.d,kB.d) x6, then V likewise.
// Slot for (s,i) at index i*4+s -> the 4 broadcast addresses of a wave hit
// disjoint banks (28*s mod 32 = 0,28,24,20). Inner loop per key-pair:
// 6 v_pk_fma (dot) + 2 v_exp + 1 pk_add + 6 v_pk_fma (acc) + 6 ds_read_b128.
#define QB 128
#define SPLIT 4
#define NPAIR 128          // key pairs per split
#define SLOTF 28           // floats per slot (24 used + 4 pad)

__global__ __launch_bounds__(512, 4) void attn_kernel(
    const float* __restrict__ Q, const float* __restrict__ K,
    const float* __restrict__ V, float* __restrict__ O) {
  __shared__ __align__(16) float KV[TT / 2 * SLOTF];  // 512 slots * 112 B = 56 KB
  const int tile = blockIdx.x & 7;
  const int bh = blockIdx.x >> 3;
  const float* __restrict__ Kh = K + (size_t)bh * TT * HD;
  const float* __restrict__ Vh = V + (size_t)bh * TT * HD;

  // ---- staging: thread t owns pair (s = t&3, i = t>>2), keys kA=s*256+2i, kA+1
  {
    const int t = threadIdx.x;
    const int ss = t & 3, ii = t >> 2;
    const int kA = ss * (TT / SPLIT) + 2 * ii;
    const float4* __restrict__ kg = (const float4*)(Kh + (size_t)kA * HD);
    const float4* __restrict__ vg = (const float4*)(Vh + (size_t)kA * HD);
    float4 K0 = kg[0], K1 = kg[1], K2 = kg[2];   // rows kA, kA+1 (12 floats)
    float4 V0 = vg[0], V1 = vg[1], V2 = vg[2];
    float4* __restrict__ slot = (float4*)&KV[(ii * SPLIT + ss) * SLOTF];
    slot[0] = make_float4(K0.x, K1.z, K0.y, K1.w);  // d0(A,B), d1(A,B)
    slot[1] = make_float4(K0.z, K2.x, K0.w, K2.y);  // d2, d3
    slot[2] = make_float4(K1.x, K2.z, K1.y, K2.w);  // d4, d5
    slot[3] = make_float4(V0.x, V1.z, V0.y, V1.w);
    slot[4] = make_float4(V0.z, V2.x, V0.w, V2.y);
    slot[5] = make_float4(V1.x, V2.z, V1.y, V2.w);
  }
  __syncthreads();

  const int s = threadIdx.x & 3;
  const int q = tile * QB + (threadIdx.x >> 2);
  const float* __restrict__ Qr = Q + ((size_t)bh * TT + q) * HD;
  v2f qd[HD];
#pragma unroll
  for (int d = 0; d < HD; ++d) {
    const float qv = Qr[d];
    qd[d].x = qv; qd[d].y = qv;
  }

  v2f l2 = {0.f, 0.f};
  v2f acc2[HD];
#pragma unroll
  for (int d = 0; d < HD; ++d) { acc2[d].x = 0.f; acc2[d].y = 0.f; }

#pragma unroll 2
  for (int i = 0; i < NPAIR; ++i) {
    const float4* __restrict__ p4 = (const float4*)&KV[((i << 2) + s) * SLOTF];
    const float4 A = p4[0], B = p4[1], C = p4[2];
    const float4 D = p4[3], E = p4[4], F = p4[5];
    v2f t2 = {-MBIAS, -MBIAS};
    v2f u;
    u.x = A.x; u.y = A.y; t2 = __builtin_elementwise_fma(qd[0], u, t2);
    u.x = A.z; u.y = A.w; t2 = __builtin_elementwise_fma(qd[1], u, t2);
    u.x = B.x; u.y = B.y; t2 = __builtin_elementwise_fma(qd[2], u, t2);
    u.x = B.z; u.y = B.w; t2 = __builtin_elementwise_fma(qd[3], u, t2);
    u.x = C.x; u.y = C.y; t2 = __builtin_elementwise_fma(qd[4], u, t2);
    u.x = C.z; u.y = C.w; t2 = __builtin_elementwise_fma(qd[5], u, t2);
    v2f p2;
    p2.x = __builtin_amdgcn_exp2f(t2.x);
    p2.y = __builtin_amdgcn_exp2f(t2.y);
    l2 += p2;
    u.x = D.x; u.y = D.y; acc2[0] = __builtin_elementwise_fma(p2, u, acc2[0]);
    u.x = D.z; u.y = D.w; acc2[1] = __builtin_elementwise_fma(p2, u, acc2[1]);
    u.x = E.x; u.y = E.y; acc2[2] = __builtin_elementwise_fma(p2, u, acc2[2]);
    u.x = E.z; u.y = E.w; acc2[3] = __builtin_elementwise_fma(p2, u, acc2[3]);
    u.x = F.x; u.y = F.y; acc2[4] = __builtin_elementwise_fma(p2, u, acc2[4]);
    u.x = F.z; u.y = F.w; acc2[5] = __builtin_elementwise_fma(p2, u, acc2[5]);
  }

  float l = l2.x + l2.y;
  float a0 = acc2[0].x + acc2[0].y;
  float a1 = acc2[1].x + acc2[1].y;
  float a2 = acc2[2].x + acc2[2].y;
  float a3 = acc2[3].x + acc2[3].y;
  float a4 = acc2[4].x + acc2[4].y;
  float a5 = acc2[5].x + acc2[5].y;

#define RED(v)                 \
  v += __shfl_xor(v, 1);       \
  v += __shfl_xor(v, 2);
  RED(l) RED(a0) RED(a1) RED(a2) RED(a3) RED(a4) RED(a5)
#undef RED

  if (s == 0) {
    const float inv = 1.f / l;
    const int b = bh >> 2, h = bh & (NH - 1);
    float* __restrict__ Or = O + ((size_t)(b * TT + q)) * DM + h * HD;
    Or[0] = a0 * inv;
    Or[1] = a1 * inv;
    Or[2] = a2 * inv;
    Or[3] = a3 * inv;
    Or[4] = a4 * inv;
    Or[5] = a5 * inv;
  }
}

// ---------- kernel 3: output projection (unchanged from round 3) ----------
__global__ __launch_bounds__(256, 4) void outproj_kernel(
    const float* __restrict__ O, const float* __restrict__ Wo,
    float* __restrict__ out) {
  __shared__ float w[DM * DM];
  for (int i = threadIdx.x; i < DM * DM; i += 256) w[i] = Wo[i];
  __syncthreads();
  const int rl = threadIdx.x >> 3, u = threadIdx.x & 7;
  const int r = blockIdx.x * 32 + rl;
  float x[DM];
  const float4* __restrict__ xr = (const float4*)(O + (size_t)r * DM);
#pragma unroll
  for (int i = 0; i < 6; ++i) {
    float4 t = xr[i];
    x[4 * i] = t.x; x[4 * i + 1] = t.y; x[4 * i + 2] = t.z; x[4 * i + 3] = t.w;
  }
#pragma unroll
  for (int jj = 0; jj < 3; ++jj) {
    const int j = u * 3 + jj;
    float a = 0.f;
#pragma unroll
    for (int c = 0; c < DM; ++c) a = fmaf(x[c], w[j * DM + c], a);
    out[(size_t)r * DM + j] = a;
  }
}

// ---------- launch ----------
extern "C" void kernel_launch(void* const* d_in, const int* in_sizes, int n_in,
                              void* d_out, int out_size, void* d_ws, size_t ws_size,
                              hipStream_t stream) {
  const float* X = (const float*)d_in[0];
  const float* Xen = (const float*)d_in[1];
  // d_in[2] = I_m : dead in the reference (masked_fill result discarded)
  const float* Wq = (const float*)d_in[3];
  const float* Wk = (const float*)d_in[4];
  const float* Wv = (const float*)d_in[5];
  const float* Wo = (const float*)d_in[6];

  float* Q = (float*)d_ws;
  float* K = Q + (size_t)NB * TT * DM;
  float* V = K + (size_t)NB * TT * DM;
  float* O = V + (size_t)NB * TT * DM;

  qkv_kernel<<<(NB * TT / 64) * 3, 256, 0, stream>>>(X, Xen, Wq, Wk, Wv, Q, K, V);
  attn_kernel<<<NB * NH * (TT / QB), 512, 0, stream>>>(Q, K, V, O);
  outproj_kernel<<<NB * TT / 32, 256, 0, stream>>>(O, Wo, (float*)d_out);
}

// Round 5
// 42.255 us; speedup vs baseline: 2.7534x; 1.0866x over previous
//
#include <hip/hip_runtime.h>
#include <hip/hip_bf16.h>

#define NB 16      // batch
#define TT 1024    // Tq == Tk
#define NH 4       // heads
#define HD 6       // head dim
#define DM 24      // model dim

// (1/sqrt(6)) * log2(e) -- folded into Wq so attention works in exp2 domain
#define QSC 0.5889785f
// conservative upper bound on any log2-domain score; softmax invariant to it
#define MBIAS 32.0f

typedef float v2f __attribute__((ext_vector_type(2)));

// ---------- kernel 1: fused Q/K/V projection (unchanged) ----------
__global__ __launch_bounds__(256, 4) void qkv_kernel(
    const float* __restrict__ X, const float* __restrict__ Xen,
    const float* __restrict__ Wq, const float* __restrict__ Wk,
    const float* __restrict__ Wv,
    float* __restrict__ Q, float* __restrict__ K, float* __restrict__ V) {
  __shared__ float w[DM * DM];
  const int mat = blockIdx.x % 3;
  const int rb = (blockIdx.x / 3) * 64;
  const float* __restrict__ W = (mat == 0) ? Wq : (mat == 1 ? Wk : Wv);
  const float* __restrict__ Xs = (mat == 0) ? X : Xen;
  float* __restrict__ Out = (mat == 0) ? Q : (mat == 1 ? K : V);
  const float sc = (mat == 0) ? QSC : 1.0f;
  for (int i = threadIdx.x; i < DM * DM; i += 256) w[i] = W[i] * sc;
  __syncthreads();

  const int rl = threadIdx.x >> 2;
  const int h = threadIdx.x & 3;
  const int r = rb + rl;
  float x[DM];
  const float4* __restrict__ xr = (const float4*)(Xs + (size_t)r * DM);
#pragma unroll
  for (int i = 0; i < 6; ++i) {
    float4 t = xr[i];
    x[4 * i] = t.x; x[4 * i + 1] = t.y; x[4 * i + 2] = t.z; x[4 * i + 3] = t.w;
  }
  const int b = r >> 10, t = r & (TT - 1);
  float o[HD];
#pragma unroll
  for (int d = 0; d < HD; ++d) {
    const int j = h * HD + d;
    float a = 0.f;
#pragma unroll
    for (int c = 0; c < DM; ++c) a = fmaf(x[c], w[j * DM + c], a);
    o[d] = a;
  }
  float* __restrict__ Or = Out + (((size_t)(b * NH + h) * TT) + t) * HD;
#pragma unroll
  for (int d = 0; d < HD; ++d) Or[d] = o[d];
}

// ---------- kernel 2: attention, NQ=4 queries per thread ----------
// Round-4 post-mortem: LDS return-BW bound (768 ds_read_b128/wave, ~41us).
// Fix: each thread handles 4 queries -> each LDS read feeds 4 dot products
// (LDS traffic /4). Block 256 thr = 32 query-groups x 8 key-splits;
// 128 queries/block, grid = 64 bh x 8 tiles = 512 blocks (2/CU).
// Slot per key-pair: 24 floats (96 B), dim-interleaved K then V. Broadcast
// addresses of the 8 splits hit bank groups {0,24,16,8} x2 -> 2-way
// conflicts only (free per m136). Inner loop per key-pair: 6 ds_read_b128 +
// 4x(6 pk_fma + 2 exp + 1 pk_add + 6 pk_fma).
#define QB 128     // queries per block
#define SPLIT 8
#define NQ 4
#define NPAIR 64   // key pairs per split (128 keys / 2)
#define SLOTF 24

__global__ __launch_bounds__(256, 2) void attn_kernel(
    const float* __restrict__ Q, const float* __restrict__ K,
    const float* __restrict__ V, float* __restrict__ O) {
  __shared__ __align__(16) float KV[(TT / 2) * SLOTF];  // 512 slots * 96 B = 48 KB
  const int tile = blockIdx.x & 7;
  const int bh = blockIdx.x >> 3;
  const float* __restrict__ Kh = K + (size_t)bh * TT * HD;
  const float* __restrict__ Vh = V + (size_t)bh * TT * HD;

  // ---- staging: pair p covers keys (2p, 2p+1); slot = (p&63)*8 + (p>>6)
  for (int p = threadIdx.x; p < TT / 2; p += 256) {
    const int s = p >> 6, i = p & 63;
    const float4* __restrict__ kg = (const float4*)(Kh + (size_t)p * 12);
    const float4* __restrict__ vg = (const float4*)(Vh + (size_t)p * 12);
    float4 K0 = kg[0], K1 = kg[1], K2 = kg[2];
    float4 V0 = vg[0], V1 = vg[1], V2 = vg[2];
    float4* __restrict__ slot = (float4*)&KV[(i * SPLIT + s) * SLOTF];
    slot[0] = make_float4(K0.x, K1.z, K0.y, K1.w);  // kA0,kB0,kA1,kB1
    slot[1] = make_float4(K0.z, K2.x, K0.w, K2.y);  // kA2,kB2,kA3,kB3
    slot[2] = make_float4(K1.x, K2.z, K1.y, K2.w);  // kA4,kB4,kA5,kB5
    slot[3] = make_float4(V0.x, V1.z, V0.y, V1.w);
    slot[4] = make_float4(V0.z, V2.x, V0.w, V2.y);
    slot[5] = make_float4(V1.x, V2.z, V1.y, V2.w);
  }
  __syncthreads();

  const int s = threadIdx.x & 7;   // key split
  const int g = threadIdx.x >> 3;  // query group 0..31
  const int q0 = tile * QB + g * NQ;

  // load 4 query rows (24 consecutive floats, 16B-aligned)
  float qa[NQ * HD];
  {
    const float4* __restrict__ qr =
        (const float4*)(Q + ((size_t)bh * TT + q0) * HD);
#pragma unroll
    for (int i = 0; i < 6; ++i) {
      float4 t = qr[i];
      qa[4 * i] = t.x; qa[4 * i + 1] = t.y;
      qa[4 * i + 2] = t.z; qa[4 * i + 3] = t.w;
    }
  }
  v2f qd[NQ][HD];
#pragma unroll
  for (int j = 0; j < NQ; ++j)
#pragma unroll
    for (int d = 0; d < HD; ++d) {
      const float qv = qa[j * HD + d];
      qd[j][d].x = qv; qd[j][d].y = qv;
    }

  v2f l2[NQ];
  v2f acc[NQ][HD];
#pragma unroll
  for (int j = 0; j < NQ; ++j) {
    l2[j].x = 0.f; l2[j].y = 0.f;
#pragma unroll
    for (int d = 0; d < HD; ++d) { acc[j][d].x = 0.f; acc[j][d].y = 0.f; }
  }

#pragma unroll 2
  for (int i = 0; i < NPAIR; ++i) {
    const float4* __restrict__ p4 =
        (const float4*)&KV[((i << 3) + s) * SLOTF];
    const float4 A = p4[0], B = p4[1], C = p4[2];
    const float4 D = p4[3], E = p4[4], F = p4[5];
    v2f kk[HD], vv[HD];
    kk[0].x = A.x; kk[0].y = A.y; kk[1].x = A.z; kk[1].y = A.w;
    kk[2].x = B.x; kk[2].y = B.y; kk[3].x = B.z; kk[3].y = B.w;
    kk[4].x = C.x; kk[4].y = C.y; kk[5].x = C.z; kk[5].y = C.w;
    vv[0].x = D.x; vv[0].y = D.y; vv[1].x = D.z; vv[1].y = D.w;
    vv[2].x = E.x; vv[2].y = E.y; vv[3].x = E.z; vv[3].y = E.w;
    vv[4].x = F.x; vv[4].y = F.y; vv[5].x = F.z; vv[5].y = F.w;
#pragma unroll
    for (int j = 0; j < NQ; ++j) {
      v2f t2 = {-MBIAS, -MBIAS};
#pragma unroll
      for (int d = 0; d < HD; ++d)
        t2 = __builtin_elementwise_fma(qd[j][d], kk[d], t2);
      v2f p2;
      p2.x = __builtin_amdgcn_exp2f(t2.x);
      p2.y = __builtin_amdgcn_exp2f(t2.y);
      l2[j] += p2;
#pragma unroll
      for (int d = 0; d < HD; ++d)
        acc[j][d] = __builtin_elementwise_fma(p2, vv[d], acc[j][d]);
    }
  }

  // fold packed halves, then reduce across the 8 key-splits (lane bits 0-2)
  const int b = bh >> 2, h = bh & (NH - 1);
#pragma unroll
  for (int j = 0; j < NQ; ++j) {
    float l = l2[j].x + l2[j].y;
    float a[HD];
#pragma unroll
    for (int d = 0; d < HD; ++d) a[d] = acc[j][d].x + acc[j][d].y;
#define RED(v) v += __shfl_xor(v, 1); v += __shfl_xor(v, 2); v += __shfl_xor(v, 4);
    RED(l)
#pragma unroll
    for (int d = 0; d < HD; ++d) { RED(a[d]) }
#undef RED
    if (s == 0) {
      const float inv = 1.f / l;
      float* __restrict__ Or =
          O + ((size_t)(b * TT + q0 + j)) * DM + h * HD;
#pragma unroll
      for (int d = 0; d < HD; ++d) Or[d] = a[d] * inv;
    }
  }
}

// ---------- kernel 3: output projection (unchanged) ----------
__global__ __launch_bounds__(256, 4) void outproj_kernel(
    const float* __restrict__ O, const float* __restrict__ Wo,
    float* __restrict__ out) {
  __shared__ float w[DM * DM];
  for (int i = threadIdx.x; i < DM * DM; i += 256) w[i] = Wo[i];
  __syncthreads();
  const int rl = threadIdx.x >> 3, u = threadIdx.x & 7;
  const int r = blockIdx.x * 32 + rl;
  float x[DM];
  const float4* __restrict__ xr = (const float4*)(O + (size_t)r * DM);
#pragma unroll
  for (int i = 0; i < 6; ++i) {
    float4 t = xr[i];
    x[4 * i] = t.x; x[4 * i + 1] = t.y; x[4 * i + 2] = t.z; x[4 * i + 3] = t.w;
  }
#pragma unroll
  for (int jj = 0; jj < 3; ++jj) {
    const int j = u * 3 + jj;
    float a = 0.f;
#pragma unroll
    for (int c = 0; c < DM; ++c) a = fmaf(x[c], w[j * DM + c], a);
    out[(size_t)r * DM + j] = a;
  }
}

// ---------- launch ----------
extern "C" void kernel_launch(void* const* d_in, const int* in_sizes, int n_in,
                              void* d_out, int out_size, void* d_ws, size_t ws_size,
                              hipStream_t stream) {
  const float* X = (const float*)d_in[0];
  const float* Xen = (const float*)d_in[1];
  // d_in[2] = I_m : dead in the reference (masked_fill result discarded)
  const float* Wq = (const float*)d_in[3];
  const float* Wk = (const float*)d_in[4];
  const float* Wv = (const float*)d_in[5];
  const float* Wo = (const float*)d_in[6];

  float* Q = (float*)d_ws;
  float* K = Q + (size_t)NB * TT * DM;
  float* V = K + (size_t)NB * TT * DM;
  float* O = V + (size_t)NB * TT * DM;

  qkv_kernel<<<(NB * TT / 64) * 3, 256, 0, stream>>>(X, Xen, Wq, Wk, Wv, Q, K, V);
  attn_kernel<<<NB * NH * (TT / QB), 256, 0, stream>>>(Q, K, V, O);
  outproj_kernel<<<NB * TT / 32, 256, 0, stream>>>(O, Wo, (float*)d_out);
}

// Round 6
// 41.160 us; speedup vs baseline: 2.8266x; 1.0266x over previous
//
#include <hip/hip_runtime.h>
#include <hip/hip_bf16.h>

#define NB 16      // batch
#define TT 1024    // Tq == Tk
#define NH 4       // heads
#define HD 6       // head dim
#define DM 24      // model dim

// (1/sqrt(6)) * log2(e) -- folded into Wq so attention works in exp2 domain
#define QSC 0.5889785f
// fixed conservative bias in log2 domain; both key-split blocks use the SAME
// bias, so partial (l, acc) combine by plain addition and softmax is exact.
#define MBIAS 32.0f

typedef float v2f __attribute__((ext_vector_type(2)));

// ---------- kernel 1: fused Q/K/V projection (unchanged) ----------
__global__ __launch_bounds__(256, 4) void qkv_kernel(
    const float* __restrict__ X, const float* __restrict__ Xen,
    const float* __restrict__ Wq, const float* __restrict__ Wk,
    const float* __restrict__ Wv,
    float* __restrict__ Q, float* __restrict__ K, float* __restrict__ V) {
  __shared__ float w[DM * DM];
  const int mat = blockIdx.x % 3;
  const int rb = (blockIdx.x / 3) * 64;
  const float* __restrict__ W = (mat == 0) ? Wq : (mat == 1 ? Wk : Wv);
  const float* __restrict__ Xs = (mat == 0) ? X : Xen;
  float* __restrict__ Out = (mat == 0) ? Q : (mat == 1 ? K : V);
  const float sc = (mat == 0) ? QSC : 1.0f;
  for (int i = threadIdx.x; i < DM * DM; i += 256) w[i] = W[i] * sc;
  __syncthreads();

  const int rl = threadIdx.x >> 2;
  const int h = threadIdx.x & 3;
  const int r = rb + rl;
  float x[DM];
  const float4* __restrict__ xr = (const float4*)(Xs + (size_t)r * DM);
#pragma unroll
  for (int i = 0; i < 6; ++i) {
    float4 t = xr[i];
    x[4 * i] = t.x; x[4 * i + 1] = t.y; x[4 * i + 2] = t.z; x[4 * i + 3] = t.w;
  }
  const int b = r >> 10, t = r & (TT - 1);
  float o[HD];
#pragma unroll
  for (int d = 0; d < HD; ++d) {
    const int j = h * HD + d;
    float a = 0.f;
#pragma unroll
    for (int c = 0; c < DM; ++c) a = fmaf(x[c], w[j * DM + c], a);
    o[d] = a;
  }
  float* __restrict__ Or = Out + (((size_t)(b * NH + h) * TT) + t) * HD;
#pragma unroll
  for (int d = 0; d < HD; ++d) Or[d] = o[d];
}

// ---------- kernel 2: attention (partial, key-split across blocks) ----------
// Round-5 post-mortem: 150+ VGPR -> 2 waves/SIMD -> LDS-latency-bound.
// Fix: NQ=2 (state ~110 VGPR peak), __launch_bounds__(256,4) (<=128 VGPR ->
// 4 waves/SIMD), KSPLIT=2 key-split blocks (28KB LDS, 4 blocks/CU), and an
// explicit 1-deep software pipeline (named prefetch regs) so each pair's
// 6 ds_read_b128 hide under the previous pair's compute.
// Block: 256 thr = 64 query-groups (NQ=2 queries) x 4 lane-splits; each
// lane-split covers 64 of the block's 256 key-pairs (pairs p == s mod 4).
// Slot: 28 floats (112 B) -> the 4 broadcast addresses hit banks
// {0,28,24,20}: conflict-free. Partials (l, a0..a5) unnormalized to P.
#define QB 128
#define SPLIT 4
#define NQ 2
#define KSPLIT 2
#define KPB (TT / KSPLIT)    // 512 keys per block
#define PAIRS (KPB / 2)      // 256 pairs per block
#define PPS (PAIRS / SPLIT)  // 64 iterations per thread
#define SLOTF 28

__global__ __launch_bounds__(256, 4) void attn_kernel(
    const float* __restrict__ Q, const float* __restrict__ K,
    const float* __restrict__ V, float* __restrict__ P) {
  __shared__ __align__(16) float KV[PAIRS * SLOTF];  // 28672 B
  const int ks = blockIdx.x & 1;
  const int tile = (blockIdx.x >> 1) & 7;
  const int bh = blockIdx.x >> 4;
  const float* __restrict__ Kh = K + ((size_t)bh * TT + ks * KPB) * HD;
  const float* __restrict__ Vh = V + ((size_t)bh * TT + ks * KPB) * HD;

  // staging: thread t stages pair t (keys 2t, 2t+1 of this block's range),
  // dim-interleaved (kA.d, kB.d).
  {
    const int t = threadIdx.x;
    const float4* __restrict__ kg = (const float4*)(Kh + t * 12);
    const float4* __restrict__ vg = (const float4*)(Vh + t * 12);
    float4 K0 = kg[0], K1 = kg[1], K2 = kg[2];
    float4 V0 = vg[0], V1 = vg[1], V2 = vg[2];
    float4* __restrict__ slot = (float4*)&KV[t * SLOTF];
    slot[0] = make_float4(K0.x, K1.z, K0.y, K1.w);
    slot[1] = make_float4(K0.z, K2.x, K0.w, K2.y);
    slot[2] = make_float4(K1.x, K2.z, K1.y, K2.w);
    slot[3] = make_float4(V0.x, V1.z, V0.y, V1.w);
    slot[4] = make_float4(V0.z, V2.x, V0.w, V2.y);
    slot[5] = make_float4(V1.x, V2.z, V1.y, V2.w);
  }
  __syncthreads();

  const int s = threadIdx.x & 3;   // lane key-split
  const int g = threadIdx.x >> 2;  // query group 0..63
  const int q0 = tile * QB + g * NQ;

  // load 2 query rows (12 consecutive floats)
  float qa[NQ * HD];
  {
    const float4* __restrict__ qr =
        (const float4*)(Q + ((size_t)bh * TT + q0) * HD);
#pragma unroll
    for (int i = 0; i < 3; ++i) {
      float4 t = qr[i];
      qa[4 * i] = t.x; qa[4 * i + 1] = t.y;
      qa[4 * i + 2] = t.z; qa[4 * i + 3] = t.w;
    }
  }
  v2f qd[NQ][HD];
#pragma unroll
  for (int j = 0; j < NQ; ++j)
#pragma unroll
    for (int d = 0; d < HD; ++d) {
      const float qv = qa[j * HD + d];
      qd[j][d].x = qv; qd[j][d].y = qv;
    }

  v2f l2[NQ];
  v2f acc[NQ][HD];
#pragma unroll
  for (int j = 0; j < NQ; ++j) {
    l2[j].x = 0.f; l2[j].y = 0.f;
#pragma unroll
    for (int d = 0; d < HD; ++d) { acc[j][d].x = 0.f; acc[j][d].y = 0.f; }
  }

  auto compute = [&](float4 A, float4 B, float4 C, float4 D, float4 E,
                     float4 F) {
    v2f kk[HD], vv[HD];
    kk[0].x = A.x; kk[0].y = A.y; kk[1].x = A.z; kk[1].y = A.w;
    kk[2].x = B.x; kk[2].y = B.y; kk[3].x = B.z; kk[3].y = B.w;
    kk[4].x = C.x; kk[4].y = C.y; kk[5].x = C.z; kk[5].y = C.w;
    vv[0].x = D.x; vv[0].y = D.y; vv[1].x = D.z; vv[1].y = D.w;
    vv[2].x = E.x; vv[2].y = E.y; vv[3].x = E.z; vv[3].y = E.w;
    vv[4].x = F.x; vv[4].y = F.y; vv[5].x = F.z; vv[5].y = F.w;
#pragma unroll
    for (int j = 0; j < NQ; ++j) {
      v2f t2 = {-MBIAS, -MBIAS};
#pragma unroll
      for (int d = 0; d < HD; ++d)
        t2 = __builtin_elementwise_fma(qd[j][d], kk[d], t2);
      v2f p2;
      p2.x = __builtin_amdgcn_exp2f(t2.x);
      p2.y = __builtin_amdgcn_exp2f(t2.y);
      l2[j] += p2;
#pragma unroll
      for (int d = 0; d < HD; ++d)
        acc[j][d] = __builtin_elementwise_fma(p2, vv[d], acc[j][d]);
    }
  };

  // software pipeline: prefetch pair i+1 (this lane's next slot: +4 slots)
  const float4* __restrict__ p4 = (const float4*)&KV[s * SLOTF];
  float4 A = p4[0], B = p4[1], C = p4[2], D = p4[3], E = p4[4], F = p4[5];
  for (int i = 0; i < PPS - 1; ++i) {
    const float4* __restrict__ n4 = p4 + SPLIT * (SLOTF / 4);
    float4 nA = n4[0], nB = n4[1], nC = n4[2], nD = n4[3], nE = n4[4],
           nF = n4[5];
    compute(A, B, C, D, E, F);
    A = nA; B = nB; C = nC; D = nD; E = nE; F = nF;
    p4 = n4;
  }
  compute(A, B, C, D, E, F);

  // reduce across the 4 lane-splits, write unnormalized partials
#pragma unroll
  for (int j = 0; j < NQ; ++j) {
    float l = l2[j].x + l2[j].y;
    float a0 = acc[j][0].x + acc[j][0].y;
    float a1 = acc[j][1].x + acc[j][1].y;
    float a2 = acc[j][2].x + acc[j][2].y;
    float a3 = acc[j][3].x + acc[j][3].y;
    float a4 = acc[j][4].x + acc[j][4].y;
    float a5 = acc[j][5].x + acc[j][5].y;
#define RED(v) v += __shfl_xor(v, 1); v += __shfl_xor(v, 2);
    RED(l) RED(a0) RED(a1) RED(a2) RED(a3) RED(a4) RED(a5)
#undef RED
    if (s == 0) {
      float* __restrict__ Pr =
          P + (((size_t)(bh * KSPLIT + ks)) * TT + (q0 + j)) * 8;
      ((float4*)Pr)[0] = make_float4(l, a0, a1, a2);
      ((float4*)Pr)[1] = make_float4(a3, a4, a5, 0.f);
    }
  }
}

// ---------- kernel 3: combine partials + output projection ----------
// Block handles 32 rows. Phase A: 128 (row,head) units x 2 threads (one per
// key-split partial); shfl_xor(1) folds, normalize into LDS. Phase B: 8
// threads/row x 3 outputs: 24x24 projection.
__global__ __launch_bounds__(256, 4) void combine_outproj_kernel(
    const float* __restrict__ P, const float* __restrict__ Wo,
    float* __restrict__ out) {
  __shared__ float w[DM * DM];
  __shared__ float o[32][25];
  for (int i = threadIdx.x; i < DM * DM; i += 256) w[i] = Wo[i];
  const int r0 = blockIdx.x * 32;
  {
    const int unit = threadIdx.x >> 1, e = threadIdx.x & 1;
    const int rl = unit >> 2, h = unit & 3;
    const int r = r0 + rl, b = r >> 10, t = r & (TT - 1);
    const int bh = b * NH + h;
    const float4* __restrict__ pp =
        (const float4*)(P + (((size_t)(bh * KSPLIT + e)) * TT + t) * 8);
    float4 x0 = pp[0], x1 = pp[1];
    float l = x0.x, a0 = x0.y, a1 = x0.z, a2 = x0.w;
    float a3 = x1.x, a4 = x1.y, a5 = x1.z;
    l += __shfl_xor(l, 1);
    a0 += __shfl_xor(a0, 1);
    a1 += __shfl_xor(a1, 1);
    a2 += __shfl_xor(a2, 1);
    a3 += __shfl_xor(a3, 1);
    a4 += __shfl_xor(a4, 1);
    a5 += __shfl_xor(a5, 1);
    if (e == 0) {
      const float inv = 1.f / l;
      o[rl][h * HD + 0] = a0 * inv;
      o[rl][h * HD + 1] = a1 * inv;
      o[rl][h * HD + 2] = a2 * inv;
      o[rl][h * HD + 3] = a3 * inv;
      o[rl][h * HD + 4] = a4 * inv;
      o[rl][h * HD + 5] = a5 * inv;
    }
  }
  __syncthreads();
  const int rl = threadIdx.x >> 3, u = threadIdx.x & 7;
  const int r = r0 + rl;
  float x[DM];
#pragma unroll
  for (int c = 0; c < DM; ++c) x[c] = o[rl][c];
#pragma unroll
  for (int jj = 0; jj < 3; ++jj) {
    const int j = u * 3 + jj;
    float a = 0.f;
#pragma unroll
    for (int c = 0; c < DM; ++c) a = fmaf(x[c], w[j * DM + c], a);
    out[(size_t)r * DM + j] = a;
  }
}

// ---------- launch ----------
extern "C" void kernel_launch(void* const* d_in, const int* in_sizes, int n_in,
                              void* d_out, int out_size, void* d_ws, size_t ws_size,
                              hipStream_t stream) {
  const float* X = (const float*)d_in[0];
  const float* Xen = (const float*)d_in[1];
  // d_in[2] = I_m : dead in the reference (masked_fill result discarded)
  const float* Wq = (const float*)d_in[3];
  const float* Wk = (const float*)d_in[4];
  const float* Wv = (const float*)d_in[5];
  const float* Wo = (const float*)d_in[6];

  float* Q = (float*)d_ws;
  float* K = Q + (size_t)NB * TT * DM;
  float* V = K + (size_t)NB * TT * DM;
  float* P = V + (size_t)NB * TT * DM;  // [64 bh][2 ks][1024 q][8]

  qkv_kernel<<<(NB * TT / 64) * 3, 256, 0, stream>>>(X, Xen, Wq, Wk, Wv, Q, K, V);
  attn_kernel<<<NB * NH * (TT / QB) * KSPLIT, 256, 0, stream>>>(Q, K, V, P);
  combine_outproj_kernel<<<NB * TT / 32, 256, 0, stream>>>(P, Wo, (float*)d_out);
}

// Round 7
// 38.520 us; speedup vs baseline: 3.0204x; 1.0685x over previous
//
#include <hip/hip_runtime.h>
#include <hip/hip_bf16.h>

#define NB 16      // batch
#define TT 1024    // Tq == Tk
#define NH 4       // heads
#define HD 6       // head dim
#define DM 24      // model dim

// (1/sqrt(6)) * log2(e) -- folded into Wq so attention works in exp2 domain
#define QSC 0.5889785f
// fixed conservative bias in log2 domain; all key-split blocks use the SAME
// bias, so partials (l, acc) combine by plain addition; softmax exact.
#define MBIAS 32.0f

typedef float v2f __attribute__((ext_vector_type(2)));

// ---------------- kernel 1: fused QKV projection + attention ----------------
// R6 post-mortem: attn loop is latency-hidden at 4 waves/SIMD (~10-14us);
// the budget is dominated by launch gaps + the 31MB Q/K/V global round-trip.
// Fix: each block computes its own K/V half (head slice) directly into the
// LDS slot layout, and its own 2 Q rows. 3 kernels -> 2.
// Grid: 64 bh x 8 qtiles x 2 ksplits = 1024 blocks (4/CU, fully resident).
// Block: 256 thr = 64 query-groups (NQ=2) x 4 lane-splits.
// LDS: 256 pair-slots x 28 floats (112B; 4 broadcast addrs hit banks
// {0,28,24,20} -> conflict-free) + 432-float weight slice = 30.1 KB.
#define QB 128
#define SPLIT 4
#define NQ 2
#define KSPLIT 2
#define KPB (TT / KSPLIT)    // 512 keys per block
#define PAIRS (KPB / 2)      // 256 pairs per block
#define PPS (PAIRS / SPLIT)  // 64 iterations per thread
#define SLOTF 28

__global__ __launch_bounds__(256, 4) void fused_attn_kernel(
    const float* __restrict__ X, const float* __restrict__ Xen,
    const float* __restrict__ Wq, const float* __restrict__ Wk,
    const float* __restrict__ Wv, float* __restrict__ P) {
  __shared__ __align__(16) float KVs[PAIRS * SLOTF];  // 28672 B
  __shared__ __align__(16) float wl[3 * HD * DM];     // wq|wk|wv head slices

  const int ks = blockIdx.x & 1;
  const int tile = (blockIdx.x >> 1) & 7;
  const int bh = blockIdx.x >> 4;
  const int b = bh >> 2, h = bh & 3;

  // ---- stage head-slice weights: wl[m*144 + j*24 + c] = W[h*6+j][c]
  for (int i = threadIdx.x; i < 3 * HD * DM; i += 256) {
    const int m = i / (HD * DM);
    const int jc = i - m * (HD * DM);
    const float* __restrict__ Ws = (m == 0) ? Wq : (m == 1 ? Wk : Wv);
    const float v = Ws[h * HD * DM + jc];
    wl[i] = (m == 0) ? v * QSC : v;
  }

  // ---- issue this thread's X_en loads (keys 2t, 2t+1: 48 floats) early
  const int t = threadIdx.x;
  const float4* __restrict__ xe4 =
      (const float4*)(Xen + ((size_t)b * TT + ks * KPB + 2 * t) * DM);
  float4 xr[12];
#pragma unroll
  for (int i = 0; i < 12; ++i) xr[i] = xe4[i];

  __syncthreads();  // wl ready

  // ---- compute K/V for keys 2t (row A), 2t+1 (row B); packed over c-pairs
  {
    v2f xa[12], xb[12];
#pragma unroll
    for (int i = 0; i < 6; ++i) {
      xa[2 * i].x = xr[i].x;     xa[2 * i].y = xr[i].y;
      xa[2 * i + 1].x = xr[i].z; xa[2 * i + 1].y = xr[i].w;
      xb[2 * i].x = xr[6 + i].x;     xb[2 * i].y = xr[6 + i].y;
      xb[2 * i + 1].x = xr[6 + i].z; xb[2 * i + 1].y = xr[6 + i].w;
    }
    float kA[HD], kB[HD], vA[HD], vB[HD];
#pragma unroll
    for (int d = 0; d < HD; ++d) {
      const v2f* __restrict__ wk2 = (const v2f*)&wl[(HD + d) * DM];
      const v2f* __restrict__ wv2 = (const v2f*)&wl[(2 * HD + d) * DM];
      v2f ak = {0.f, 0.f}, bk = {0.f, 0.f}, av = {0.f, 0.f}, bv = {0.f, 0.f};
#pragma unroll
      for (int p = 0; p < 12; ++p) {
        ak = __builtin_elementwise_fma(xa[p], wk2[p], ak);
        bk = __builtin_elementwise_fma(xb[p], wk2[p], bk);
        av = __builtin_elementwise_fma(xa[p], wv2[p], av);
        bv = __builtin_elementwise_fma(xb[p], wv2[p], bv);
      }
      kA[d] = ak.x + ak.y; kB[d] = bk.x + bk.y;
      vA[d] = av.x + av.y; vB[d] = bv.x + bv.y;
    }
    float4* __restrict__ slot = (float4*)&KVs[t * SLOTF];
    slot[0] = make_float4(kA[0], kB[0], kA[1], kB[1]);
    slot[1] = make_float4(kA[2], kB[2], kA[3], kB[3]);
    slot[2] = make_float4(kA[4], kB[4], kA[5], kB[5]);
    slot[3] = make_float4(vA[0], vB[0], vA[1], vB[1]);
    slot[4] = make_float4(vA[2], vB[2], vA[3], vB[3]);
    slot[5] = make_float4(vA[4], vB[4], vA[5], vB[5]);
  }

  // ---- compute this thread's 2 Q rows (redundant across the 4 s-lanes)
  const int s = t & 3;
  const int g = t >> 2;
  const int q0 = tile * QB + g * NQ;
  v2f qd[NQ][HD];
  {
    const float4* __restrict__ xq4 =
        (const float4*)(X + ((size_t)b * TT + q0) * DM);
    float4 qr[12];
#pragma unroll
    for (int i = 0; i < 12; ++i) qr[i] = xq4[i];
    v2f qa[12], qb[12];
#pragma unroll
    for (int i = 0; i < 6; ++i) {
      qa[2 * i].x = qr[i].x;     qa[2 * i].y = qr[i].y;
      qa[2 * i + 1].x = qr[i].z; qa[2 * i + 1].y = qr[i].w;
      qb[2 * i].x = qr[6 + i].x;     qb[2 * i].y = qr[6 + i].y;
      qb[2 * i + 1].x = qr[6 + i].z; qb[2 * i + 1].y = qr[6 + i].w;
    }
#pragma unroll
    for (int d = 0; d < HD; ++d) {
      const v2f* __restrict__ wq2 = (const v2f*)&wl[d * DM];
      v2f aq = {0.f, 0.f}, bq = {0.f, 0.f};
#pragma unroll
      for (int p = 0; p < 12; ++p) {
        aq = __builtin_elementwise_fma(qa[p], wq2[p], aq);
        bq = __builtin_elementwise_fma(qb[p], wq2[p], bq);
      }
      const float qA = aq.x + aq.y, qB = bq.x + bq.y;
      qd[0][d].x = qA; qd[0][d].y = qA;
      qd[1][d].x = qB; qd[1][d].y = qB;
    }
  }

  __syncthreads();  // KVs ready

  v2f l2[NQ];
  v2f acc[NQ][HD];
#pragma unroll
  for (int j = 0; j < NQ; ++j) {
    l2[j].x = 0.f; l2[j].y = 0.f;
#pragma unroll
    for (int d = 0; d < HD; ++d) { acc[j][d].x = 0.f; acc[j][d].y = 0.f; }
  }

  auto compute = [&](float4 A, float4 B, float4 C, float4 D, float4 E,
                     float4 F) {
    v2f kk[HD], vv[HD];
    kk[0].x = A.x; kk[0].y = A.y; kk[1].x = A.z; kk[1].y = A.w;
    kk[2].x = B.x; kk[2].y = B.y; kk[3].x = B.z; kk[3].y = B.w;
    kk[4].x = C.x; kk[4].y = C.y; kk[5].x = C.z; kk[5].y = C.w;
    vv[0].x = D.x; vv[0].y = D.y; vv[1].x = D.z; vv[1].y = D.w;
    vv[2].x = E.x; vv[2].y = E.y; vv[3].x = E.z; vv[3].y = E.w;
    vv[4].x = F.x; vv[4].y = F.y; vv[5].x = F.z; vv[5].y = F.w;
#pragma unroll
    for (int j = 0; j < NQ; ++j) {
      v2f t2 = {-MBIAS, -MBIAS};
#pragma unroll
      for (int d = 0; d < HD; ++d)
        t2 = __builtin_elementwise_fma(qd[j][d], kk[d], t2);
      v2f p2;
      p2.x = __builtin_amdgcn_exp2f(t2.x);
      p2.y = __builtin_amdgcn_exp2f(t2.y);
      l2[j] += p2;
#pragma unroll
      for (int d = 0; d < HD; ++d)
        acc[j][d] = __builtin_elementwise_fma(p2, vv[d], acc[j][d]);
    }
  };

  // software pipeline: prefetch pair i+1 (this lane's next slot: +4 slots)
  const float4* __restrict__ p4 = (const float4*)&KVs[s * SLOTF];
  float4 A = p4[0], B = p4[1], C = p4[2], D = p4[3], E = p4[4], F = p4[5];
  for (int i = 0; i < PPS - 1; ++i) {
    const float4* __restrict__ n4 = p4 + SPLIT * (SLOTF / 4);
    float4 nA = n4[0], nB = n4[1], nC = n4[2], nD = n4[3], nE = n4[4],
           nF = n4[5];
    compute(A, B, C, D, E, F);
    A = nA; B = nB; C = nC; D = nD; E = nE; F = nF;
    p4 = n4;
  }
  compute(A, B, C, D, E, F);

  // reduce across the 4 lane-splits, write unnormalized partials
#pragma unroll
  for (int j = 0; j < NQ; ++j) {
    float l = l2[j].x + l2[j].y;
    float a0 = acc[j][0].x + acc[j][0].y;
    float a1 = acc[j][1].x + acc[j][1].y;
    float a2 = acc[j][2].x + acc[j][2].y;
    float a3 = acc[j][3].x + acc[j][3].y;
    float a4 = acc[j][4].x + acc[j][4].y;
    float a5 = acc[j][5].x + acc[j][5].y;
#define RED(v) v += __shfl_xor(v, 1); v += __shfl_xor(v, 2);
    RED(l) RED(a0) RED(a1) RED(a2) RED(a3) RED(a4) RED(a5)
#undef RED
    if (s == 0) {
      float* __restrict__ Pr =
          P + (((size_t)(bh * KSPLIT + ks)) * TT + (q0 + j)) * 8;
      ((float4*)Pr)[0] = make_float4(l, a0, a1, a2);
      ((float4*)Pr)[1] = make_float4(a3, a4, a5, 0.f);
    }
  }
}

// ---------- kernel 2: combine partials + output projection (as R6) ----------
__global__ __launch_bounds__(256, 4) void combine_outproj_kernel(
    const float* __restrict__ P, const float* __restrict__ Wo,
    float* __restrict__ out) {
  __shared__ float w[DM * DM];
  __shared__ float o[32][25];
  for (int i = threadIdx.x; i < DM * DM; i += 256) w[i] = Wo[i];
  const int r0 = blockIdx.x * 32;
  {
    const int unit = threadIdx.x >> 1, e = threadIdx.x & 1;
    const int rl = unit >> 2, h = unit & 3;
    const int r = r0 + rl, b = r >> 10, t = r & (TT - 1);
    const int bh = b * NH + h;
    const float4* __restrict__ pp =
        (const float4*)(P + (((size_t)(bh * KSPLIT + e)) * TT + t) * 8);
    float4 x0 = pp[0], x1 = pp[1];
    float l = x0.x, a0 = x0.y, a1 = x0.z, a2 = x0.w;
    float a3 = x1.x, a4 = x1.y, a5 = x1.z;
    l += __shfl_xor(l, 1);
    a0 += __shfl_xor(a0, 1);
    a1 += __shfl_xor(a1, 1);
    a2 += __shfl_xor(a2, 1);
    a3 += __shfl_xor(a3, 1);
    a4 += __shfl_xor(a4, 1);
    a5 += __shfl_xor(a5, 1);
    if (e == 0) {
      const float inv = 1.f / l;
      o[rl][h * HD + 0] = a0 * inv;
      o[rl][h * HD + 1] = a1 * inv;
      o[rl][h * HD + 2] = a2 * inv;
      o[rl][h * HD + 3] = a3 * inv;
      o[rl][h * HD + 4] = a4 * inv;
      o[rl][h * HD + 5] = a5 * inv;
    }
  }
  __syncthreads();
  const int rl = threadIdx.x >> 3, u = threadIdx.x & 7;
  const int r = r0 + rl;
  float x[DM];
#pragma unroll
  for (int c = 0; c < DM; ++c) x[c] = o[rl][c];
#pragma unroll
  for (int jj = 0; jj < 3; ++jj) {
    const int j = u * 3 + jj;
    float a = 0.f;
#pragma unroll
    for (int c = 0; c < DM; ++c) a = fmaf(x[c], w[j * DM + c], a);
    out[(size_t)r * DM + j] = a;
  }
}

// ---------- launch ----------
extern "C" void kernel_launch(void* const* d_in, const int* in_sizes, int n_in,
                              void* d_out, int out_size, void* d_ws, size_t ws_size,
                              hipStream_t stream) {
  const float* X = (const float*)d_in[0];
  const float* Xen = (const float*)d_in[1];
  // d_in[2] = I_m : dead in the reference (masked_fill result discarded)
  const float* Wq = (const float*)d_in[3];
  const float* Wk = (const float*)d_in[4];
  const float* Wv = (const float*)d_in[5];
  const float* Wo = (const float*)d_in[6];

  float* P = (float*)d_ws;  // [64 bh][2 ks][1024 q][8] = 4 MB

  fused_attn_kernel<<<NB * NH * (TT / QB) * KSPLIT, 256, 0, stream>>>(
      X, Xen, Wq, Wk, Wv, P);
  combine_outproj_kernel<<<NB * TT / 32, 256, 0, stream>>>(P, Wo,
                                                           (float*)d_out);
}

// Round 8
// 36.516 us; speedup vs baseline: 3.1861x; 1.0549x over previous
//
#include <hip/hip_runtime.h>
#include <hip/hip_bf16.h>

#define NB 16      // batch
#define TT 1024    // Tq == Tk
#define NH 4       // heads
#define HD 6       // head dim
#define DM 24      // model dim

// (1/sqrt(6)) * log2(e) -- applied to Q after projection (exp2-domain scores)
#define QSC 0.5889785f
// fixed conservative bias in log2 domain; all key-split blocks use the SAME
// bias, so partials (l, acc) combine by plain addition; softmax exact.
#define MBIAS 32.0f

typedef float v2f __attribute__((ext_vector_type(2)));

// ---------------- kernel 1: fused QKV projection + attention ----------------
// R7 post-mortem: prologue read weights from LDS per-fma (~432 ds_read_b64 /
// thread) -- more DS-pipe work than the whole main loop. DS pipe is per-CU,
// shared by 4 SIMDs: it was the bottleneck. Fix: weights are wave-uniform ->
// uniform global addresses -> s_load into SGPRs; v_pk_fma with SGPR-pair
// operands. Zero LDS for weights; single barrier.
// Grid: 64 bh x 8 qtiles x 2 ksplits = 1024 blocks (4/CU). Block: 256 thr =
// 64 query-groups (NQ=2) x 4 lane-splits. LDS: 256 pair-slots x 28 floats
// (112 B; broadcast addrs hit banks {0,28,24,20} -> conflict-free) = 28.7 KB.
#define QB 128
#define SPLIT 4
#define NQ 2
#define KSPLIT 2
#define KPB (TT / KSPLIT)    // 512 keys per block
#define PAIRS (KPB / 2)      // 256 pairs per block
#define PPS (PAIRS / SPLIT)  // 64 iterations per thread
#define SLOTF 28

__global__ __launch_bounds__(256, 4) void fused_attn_kernel(
    const float* __restrict__ X, const float* __restrict__ Xen,
    const float* __restrict__ Wq, const float* __restrict__ Wk,
    const float* __restrict__ Wv, float* __restrict__ P) {
  __shared__ __align__(16) float KVs[PAIRS * SLOTF];  // 28672 B

  const int ks = blockIdx.x & 1;
  const int tile = (blockIdx.x >> 1) & 7;
  const int bh = blockIdx.x >> 4;
  const int b = bh >> 2, h = bh & 3;
  const int t = threadIdx.x;
  const int s = t & 3;   // lane key-split
  const int g = t >> 2;  // query group 0..63
  const int q0 = tile * QB + g * NQ;

  // uniform weight slices -> scalar loads (SGPRs), no LDS
  const float* __restrict__ wqh = Wq + h * HD * DM;
  const float* __restrict__ wkh = Wk + h * HD * DM;
  const float* __restrict__ wvh = Wv + h * HD * DM;

  // packed dot of one 24-float row (6 float4, static-indexed) with a uniform
  // weight row: 12 v_pk_fma_f32 (VGPR pair x SGPR pair) + fold.
  auto dot24 = [](const float4* r, const float* __restrict__ w) -> float {
    v2f a = {0.f, 0.f};
#pragma unroll
    for (int i = 0; i < 6; ++i) {
      v2f xp, wp;
      xp.x = r[i].x; xp.y = r[i].y;
      wp.x = w[4 * i + 0]; wp.y = w[4 * i + 1];
      a = __builtin_elementwise_fma(xp, wp, a);
      xp.x = r[i].z; xp.y = r[i].w;
      wp.x = w[4 * i + 2]; wp.y = w[4 * i + 3];
      a = __builtin_elementwise_fma(xp, wp, a);
    }
    return a.x + a.y;
  };

  // ---- phase 1: K/V for keys 2t, 2t+1 -> LDS slot (dim-interleaved A,B)
  {
    const float4* __restrict__ xe4 =
        (const float4*)(Xen + ((size_t)b * TT + ks * KPB + 2 * t) * DM);
    float4 xe[12];
#pragma unroll
    for (int i = 0; i < 12; ++i) xe[i] = xe4[i];  // row A: 0..5, row B: 6..11
    float kA[HD], kB[HD], vA[HD], vB[HD];
#pragma unroll
    for (int d = 0; d < HD; ++d) {
      kA[d] = dot24(xe + 0, wkh + d * DM);
      kB[d] = dot24(xe + 6, wkh + d * DM);
      vA[d] = dot24(xe + 0, wvh + d * DM);
      vB[d] = dot24(xe + 6, wvh + d * DM);
    }
    float4* __restrict__ slot = (float4*)&KVs[t * SLOTF];
    slot[0] = make_float4(kA[0], kB[0], kA[1], kB[1]);
    slot[1] = make_float4(kA[2], kB[2], kA[3], kB[3]);
    slot[2] = make_float4(kA[4], kB[4], kA[5], kB[5]);
    slot[3] = make_float4(vA[0], vB[0], vA[1], vB[1]);
    slot[4] = make_float4(vA[2], vB[2], vA[3], vB[3]);
    slot[5] = make_float4(vA[4], vB[4], vA[5], vB[5]);
  }

  // ---- phase 2: this thread's 2 Q rows (redundant across the 4 s-lanes)
  v2f qd[NQ][HD];
  {
    const float4* __restrict__ xq4 =
        (const float4*)(X + ((size_t)b * TT + q0) * DM);
    float4 xq[12];
#pragma unroll
    for (int i = 0; i < 12; ++i) xq[i] = xq4[i];
#pragma unroll
    for (int d = 0; d < HD; ++d) {
      const float qA = dot24(xq + 0, wqh + d * DM) * QSC;
      const float qB = dot24(xq + 6, wqh + d * DM) * QSC;
      qd[0][d].x = qA; qd[0][d].y = qA;
      qd[1][d].x = qB; qd[1][d].y = qB;
    }
  }

  __syncthreads();  // KVs ready

  v2f l2[NQ];
  v2f acc[NQ][HD];
#pragma unroll
  for (int j = 0; j < NQ; ++j) {
    l2[j].x = 0.f; l2[j].y = 0.f;
#pragma unroll
    for (int d = 0; d < HD; ++d) { acc[j][d].x = 0.f; acc[j][d].y = 0.f; }
  }

  auto compute = [&](float4 A, float4 B, float4 C, float4 D, float4 E,
                     float4 F) {
    v2f kk[HD], vv[HD];
    kk[0].x = A.x; kk[0].y = A.y; kk[1].x = A.z; kk[1].y = A.w;
    kk[2].x = B.x; kk[2].y = B.y; kk[3].x = B.z; kk[3].y = B.w;
    kk[4].x = C.x; kk[4].y = C.y; kk[5].x = C.z; kk[5].y = C.w;
    vv[0].x = D.x; vv[0].y = D.y; vv[1].x = D.z; vv[1].y = D.w;
    vv[2].x = E.x; vv[2].y = E.y; vv[3].x = E.z; vv[3].y = E.w;
    vv[4].x = F.x; vv[4].y = F.y; vv[5].x = F.z; vv[5].y = F.w;
#pragma unroll
    for (int j = 0; j < NQ; ++j) {
      v2f t2 = {-MBIAS, -MBIAS};
#pragma unroll
      for (int d = 0; d < HD; ++d)
        t2 = __builtin_elementwise_fma(qd[j][d], kk[d], t2);
      v2f p2;
      p2.x = __builtin_amdgcn_exp2f(t2.x);
      p2.y = __builtin_amdgcn_exp2f(t2.y);
      l2[j] += p2;
#pragma unroll
      for (int d = 0; d < HD; ++d)
        acc[j][d] = __builtin_elementwise_fma(p2, vv[d], acc[j][d]);
    }
  };

  // software pipeline: prefetch pair i+1 (this lane's next slot: +4 slots)
  const float4* __restrict__ p4 = (const float4*)&KVs[s * SLOTF];
  float4 A = p4[0], B = p4[1], C = p4[2], D = p4[3], E = p4[4], F = p4[5];
  for (int i = 0; i < PPS - 1; ++i) {
    const float4* __restrict__ n4 = p4 + SPLIT * (SLOTF / 4);
    float4 nA = n4[0], nB = n4[1], nC = n4[2], nD = n4[3], nE = n4[4],
           nF = n4[5];
    compute(A, B, C, D, E, F);
    A = nA; B = nB; C = nC; D = nD; E = nE; F = nF;
    p4 = n4;
  }
  compute(A, B, C, D, E, F);

  // reduce across the 4 lane-splits, write unnormalized partials
#pragma unroll
  for (int j = 0; j < NQ; ++j) {
    float l = l2[j].x + l2[j].y;
    float a0 = acc[j][0].x + acc[j][0].y;
    float a1 = acc[j][1].x + acc[j][1].y;
    float a2 = acc[j][2].x + acc[j][2].y;
    float a3 = acc[j][3].x + acc[j][3].y;
    float a4 = acc[j][4].x + acc[j][4].y;
    float a5 = acc[j][5].x + acc[j][5].y;
#define RED(v) v += __shfl_xor(v, 1); v += __shfl_xor(v, 2);
    RED(l) RED(a0) RED(a1) RED(a2) RED(a3) RED(a4) RED(a5)
#undef RED
    if (s == 0) {
      float* __restrict__ Pr =
          P + (((size_t)(bh * KSPLIT + ks)) * TT + (q0 + j)) * 8;
      ((float4*)Pr)[0] = make_float4(l, a0, a1, a2);
      ((float4*)Pr)[1] = make_float4(a3, a4, a5, 0.f);
    }
  }
}

// ---------- kernel 2: combine partials + output projection (as R6/R7) ------
__global__ __launch_bounds__(256, 4) void combine_outproj_kernel(
    const float* __restrict__ P, const float* __restrict__ Wo,
    float* __restrict__ out) {
  __shared__ float w[DM * DM];
  __shared__ float o[32][25];
  for (int i = threadIdx.x; i < DM * DM; i += 256) w[i] = Wo[i];
  const int r0 = blockIdx.x * 32;
  {
    const int unit = threadIdx.x >> 1, e = threadIdx.x & 1;
    const int rl = unit >> 2, h = unit & 3;
    const int r = r0 + rl, b = r >> 10, t = r & (TT - 1);
    const int bh = b * NH + h;
    const float4* __restrict__ pp =
        (const float4*)(P + (((size_t)(bh * KSPLIT + e)) * TT + t) * 8);
    float4 x0 = pp[0], x1 = pp[1];
    float l = x0.x, a0 = x0.y, a1 = x0.z, a2 = x0.w;
    float a3 = x1.x, a4 = x1.y, a5 = x1.z;
    l += __shfl_xor(l, 1);
    a0 += __shfl_xor(a0, 1);
    a1 += __shfl_xor(a1, 1);
    a2 += __shfl_xor(a2, 1);
    a3 += __shfl_xor(a3, 1);
    a4 += __shfl_xor(a4, 1);
    a5 += __shfl_xor(a5, 1);
    if (e == 0) {
      const float inv = 1.f / l;
      o[rl][h * HD + 0] = a0 * inv;
      o[rl][h * HD + 1] = a1 * inv;
      o[rl][h * HD + 2] = a2 * inv;
      o[rl][h * HD + 3] = a3 * inv;
      o[rl][h * HD + 4] = a4 * inv;
      o[rl][h * HD + 5] = a5 * inv;
    }
  }
  __syncthreads();
  const int rl = threadIdx.x >> 3, u = threadIdx.x & 7;
  const int r = r0 + rl;
  float x[DM];
#pragma unroll
  for (int c = 0; c < DM; ++c) x[c] = o[rl][c];
#pragma unroll
  for (int jj = 0; jj < 3; ++jj) {
    const int j = u * 3 + jj;
    float a = 0.f;
#pragma unroll
    for (int c = 0; c < DM; ++c) a = fmaf(x[c], w[j * DM + c], a);
    out[(size_t)r * DM + j] = a;
  }
}

// ---------- launch ----------
extern "C" void kernel_launch(void* const* d_in, const int* in_sizes, int n_in,
                              void* d_out, int out_size, void* d_ws, size_t ws_size,
                              hipStream_t stream) {
  const float* X = (const float*)d_in[0];
  const float* Xen = (const float*)d_in[1];
  // d_in[2] = I_m : dead in the reference (masked_fill result discarded)
  const float* Wq = (const float*)d_in[3];
  const float* Wk = (const float*)d_in[4];
  const float* Wv = (const float*)d_in[5];
  const float* Wo = (const float*)d_in[6];

  float* P = (float*)d_ws;  // [64 bh][2 ks][1024 q][8] = 4 MB

  fused_attn_kernel<<<NB * NH * (TT / QB) * KSPLIT, 256, 0, stream>>>(
      X, Xen, Wq, Wk, Wv, P);
  combine_outproj_kernel<<<NB * TT / 32, 256, 0, stream>>>(P, Wo,
                                                           (float*)d_out);
}